// Round 7
// baseline (1003.868 us; speedup 1.0000x reference)
//
#include <hip/hip_runtime.h>
#include <hip/hip_bf16.h>

// CustomLMHead: C[M,N] = X[M,K] @ (Wq[N,K] * scale[N])^T
// M=2048, N=151936, K=896.
//
// Fast path: preconvert X(fp32)->bf16, Wq(int32)->bf16 into d_ws, then a
// 128x128-tile GEMM, 4 waves, BK=32, TRIPLE-buffered LDS (48 KiB) at
// 3 blocks/CU. Hardened ordering: sched_barrier(0) fences both sides of
// EVERY s_barrier; explicit lgkmcnt(0) before each buffer-recycle barrier;
// prologue drains vmcnt(0). Steady-state keeps counted vmcnt(4) lookahead.
// Fallback (small ws): reg-staging kernel with in-loop conversion.

#define M_DIM 2048
#define N_DIM 151936
#define K_DIM 896

#define BM 128
#define BN 128
#define BK 32
#define NKT (K_DIM / BK)        // 28
#define MB_CNT (M_DIM / BM)     // 16
#define NB_CNT (N_DIM / BN)     // 1187 (exact)
#define NWG (MB_CNT * NB_CNT)   // 18992, divisible by 8

typedef __attribute__((ext_vector_type(8))) short bf16x8;
typedef __attribute__((ext_vector_type(4))) float f32x4;
typedef __attribute__((ext_vector_type(4))) int   i32x4;
typedef __attribute__((ext_vector_type(4))) unsigned int u32x4;

static __device__ __forceinline__ unsigned short f2bf(float f) {
    unsigned int u = __builtin_bit_cast(unsigned int, f);
    u += 0x7FFFu + ((u >> 16) & 1u);
    return (unsigned short)(u >> 16);
}
static __device__ __forceinline__ unsigned int pack2(float lo, float hi) {
    return (unsigned int)f2bf(lo) | ((unsigned int)f2bf(hi) << 16);
}
static __device__ __forceinline__ void gload_lds16(const void* g, void* l) {
    __builtin_amdgcn_global_load_lds(
        (const __attribute__((address_space(1))) unsigned int*)g,
        (__attribute__((address_space(3))) unsigned int*)l, 16, 0, 0);
}

// ---------------- preconvert kernels ----------------

__global__ void cvt_x_kernel(const float* __restrict__ X,
                             unsigned short* __restrict__ Xb) {
    const long n8 = (long)M_DIM * K_DIM / 8;
    for (long i = (long)blockIdx.x * blockDim.x + threadIdx.x; i < n8;
         i += (long)gridDim.x * blockDim.x) {
        f32x4 a = ((const f32x4*)X)[2 * i];
        f32x4 b = ((const f32x4*)X)[2 * i + 1];
        u32x4 o;
        o[0] = pack2(a[0], a[1]); o[1] = pack2(a[2], a[3]);
        o[2] = pack2(b[0], b[1]); o[3] = pack2(b[2], b[3]);
        ((u32x4*)Xb)[i] = o;
    }
}

__global__ void cvt_w_kernel(const int* __restrict__ Wq,
                             unsigned short* __restrict__ Wb) {
    const long n8 = (long)N_DIM * K_DIM / 8;
    for (long i = (long)blockIdx.x * blockDim.x + threadIdx.x; i < n8;
         i += (long)gridDim.x * blockDim.x) {
        i32x4 a = ((const i32x4*)Wq)[2 * i];
        i32x4 b = ((const i32x4*)Wq)[2 * i + 1];
        u32x4 o;
        o[0] = pack2((float)a[0], (float)a[1]); o[1] = pack2((float)a[2], (float)a[3]);
        o[2] = pack2((float)b[0], (float)b[1]); o[3] = pack2((float)b[2], (float)b[3]);
        ((u32x4*)Wb)[i] = o;
    }
}

// ---------------- 128x128 triple-buffered GEMM ----------------
// Per tile t (buf t%3), 2 phases:
//   P0: READ A(q0)+B(buf t); stage tile t+2 -> buf (t+2)%3 (4 loads);
//       BAR_A; MFMA q0; BAR_B.
//   P1: READ A(q1); vmcnt(4) [retires tile t+1, issued 2 phases ago];
//       BAR_A (publishes t+1); MFMA q1; BAR_B.
// Every barrier is fenced with sched_barrier(0) on both sides; BAR_B also
// drains lgkmcnt(0) (my ds_reads complete before anyone can pass the
// barrier that gates this buffer's overwrite).

#define SCHED0 __builtin_amdgcn_sched_barrier(0)
#define VMCNT(N) asm volatile("s_waitcnt vmcnt(" #N ")" ::: "memory")
#define LGKM0    asm volatile("s_waitcnt lgkmcnt(0)" ::: "memory")

__global__ __launch_bounds__(256, 3)
void lmhead_gemm_3b(const unsigned short* __restrict__ Xb,
                    const unsigned short* __restrict__ Wb,
                    const float* __restrict__ S,
                    float* __restrict__ O)
{
    // [buf3][mat A=0/B=1][row 128][col 32 bf16] = 48 KiB
    __shared__ unsigned short lds[3][2][BM][BK];

    const int tid  = threadIdx.x;
    const int lane = tid & 63;
    const int wave = tid >> 6;      // 0..3
    const int wr   = wave >> 1;     // 0..1
    const int wc   = wave & 1;      // 0..1

    // XCD-chunked bijective swizzle (NWG % 8 == 0); mb fastest so the 16
    // m-blocks sharing one 128-row W strip co-locate on one XCD's L2.
    const int bid = blockIdx.x;
    const int wg  = (bid & 7) * (NWG / 8) + (bid >> 3);
    const int mb  = wg % MB_CNT;
    const int nb  = wg / MB_CNT;

    // staging: per gload_lds, 4 waves x 64 lanes x 16B = 64 rows of 64B.
    // dest row = wave*16 + (lane>>2), phys 16B-slot = lane&3.
    // T2 swizzle phys = logical ^ ((row>>1)&3) -> src slot = (l&3)^((l>>3)&3).
    const int lrow  = lane >> 2;
    const int lslot = (lane & 3) ^ ((lane >> 3) & 3);
    const unsigned short* srcA0;
    const unsigned short* srcA1;
    const unsigned short* srcB0;
    const unsigned short* srcB1;
    {
        const int r0 = wave * 16 + lrow;
        srcA0 = Xb + (size_t)(mb * BM + r0) * K_DIM + lslot * 8;
        srcA1 = srcA0 + (size_t)64 * K_DIM;
        srcB0 = Wb + (size_t)(nb * BN + r0) * K_DIM + lslot * 8;
        srcB1 = srcB0 + (size_t)64 * K_DIM;
    }

    auto stage = [&](int b3, int k0) {
        gload_lds16(srcA0 + k0, &lds[b3][0][wave * 16][0]);
        gload_lds16(srcA1 + k0, &lds[b3][0][64 + wave * 16][0]);
        gload_lds16(srcB0 + k0, &lds[b3][1][wave * 16][0]);
        gload_lds16(srcB1 + k0, &lds[b3][1][64 + wave * 16][0]);
    };

    // frag reads: row = R0 + (lane&15); phys octet = (lane>>4) ^ ((lane>>1)&3)
    const int physoff   = ((lane >> 4) ^ ((lane >> 1) & 3)) * 8;
    const int arow_base = wr * 64 + (lane & 15);
    const int brow_base = wc * 64 + (lane & 15);

    f32x4 acc[4][4];
    #pragma unroll
    for (int i = 0; i < 4; ++i)
        #pragma unroll
        for (int j = 0; j < 4; ++j)
            acc[i][j] = f32x4{0.f, 0.f, 0.f, 0.f};

    // prologue: stage tiles 0,1; full drain; publish
    stage(0, 0);
    stage(1, BK);
    SCHED0;
    VMCNT(0);
    SCHED0;
    __builtin_amdgcn_s_barrier();
    SCHED0;

    bf16x8 af[2], bf[4];

#define READ_A(B3, Q) do { \
    _Pragma("unroll") \
    for (int mf = 0; mf < 2; ++mf) \
        af[mf] = *(const bf16x8*)&lds[B3][0][arow_base + (Q)*32 + mf*16][physoff]; \
} while (0)
#define READ_B(B3) do { \
    _Pragma("unroll") \
    for (int nf = 0; nf < 4; ++nf) \
        bf[nf] = *(const bf16x8*)&lds[B3][1][brow_base + nf*16][physoff]; \
} while (0)
#define MFMA_Q(Q) do { \
    __builtin_amdgcn_s_setprio(1); \
    _Pragma("unroll") \
    for (int mf = 0; mf < 2; ++mf) { \
        _Pragma("unroll") \
        for (int nf = 0; nf < 4; ++nf) \
            acc[(Q)*2 + mf][nf] = __builtin_amdgcn_mfma_f32_16x16x32_bf16( \
                af[mf], bf[nf], acc[(Q)*2 + mf][nf], 0, 0, 0); \
    } \
    __builtin_amdgcn_s_setprio(0); \
} while (0)
#define BAR_A() do { SCHED0; __builtin_amdgcn_s_barrier(); SCHED0; } while (0)
#define BAR_B() do { SCHED0; LGKM0; SCHED0; __builtin_amdgcn_s_barrier(); SCHED0; } while (0)

    for (int t = 0; t < NKT - 2; ++t) {
        const int cur = t % 3;
        // P0
        READ_A(cur, 0); READ_B(cur);
        stage((t + 2) % 3, (t + 2) * BK);
        BAR_A();
        MFMA_Q(0);
        BAR_B();
        // P1
        READ_A(cur, 1);
        SCHED0;
        VMCNT(4);       // retires tile t+1's 4 loads (issued at (t-1).P0)
        BAR_A();        // publishes tile t+1
        MFMA_Q(1);
        BAR_B();
    }

    // peel t = NKT-2: no staging; drain remaining batch (tile NKT-1)
    {
        const int cur = (NKT - 2) % 3;
        READ_A(cur, 0); READ_B(cur);
        BAR_A();
        MFMA_Q(0);
        BAR_B();
        READ_A(cur, 1);
        SCHED0;
        VMCNT(0);       // tile NKT-1's batch, issued 2 phases ago
        BAR_A();
        MFMA_Q(1);
        BAR_B();
    }
    // peel t = NKT-1
    {
        const int cur = (NKT - 1) % 3;
        READ_A(cur, 0); READ_B(cur);
        BAR_A();
        MFMA_Q(0);
        BAR_B();
        READ_A(cur, 1);
        BAR_A();
        MFMA_Q(1);
    }

#undef READ_A
#undef READ_B
#undef MFMA_Q
#undef BAR_A
#undef BAR_B

    // ---- LDS-coalesced epilogue (full __syncthreads drains) ----
    // Reuse staging LDS as float[64][128] (32 KiB), 2 passes (row halves).
    // Writes: scaled, XOR-swizzled pcol = col ^ (qw<<4) (2-way = free).
    // Reads: f32x4, 2 rows/instr, contiguous -> full 128B-line global stores.
    __syncthreads();   // all waves' K-loop work fully drained

    float* lf = (float*)&lds[0][0][0][0];
    const int qw = lane >> 4;     // 0..3
    const int li = lane & 15;

    float scn[4];
    #pragma unroll
    for (int nf = 0; nf < 4; ++nf)
        scn[nf] = S[nb * BN + wc * 64 + nf * 16 + li];

    #pragma unroll
    for (int p = 0; p < 2; ++p) {
        if (p) __syncthreads();   // pass-0 reads before pass-1 writes
        if (wr == p) {
            #pragma unroll
            for (int a = 0; a < 4; ++a) {
                #pragma unroll
                for (int nf = 0; nf < 4; ++nf) {
                    #pragma unroll
                    for (int r = 0; r < 4; ++r) {
                        const int lr   = a * 16 + qw * 4 + r;
                        const int col  = wc * 64 + nf * 16 + li;
                        const int pcol = col ^ (qw << 4);
                        lf[lr * 128 + pcol] = acc[a][nf][r] * scn[nf];
                    }
                }
            }
        }
        __syncthreads();
        #pragma unroll
        for (int i = 0; i < 8; ++i) {
            const int row = wave * 16 + i * 2 + (lane >> 5);
            const int q   = (row >> 2) & 3;
            const int pch = (lane & 31) ^ (q << 2);
            f32x4 v = *(const f32x4*)&lf[row * 128 + pch * 4];
            const size_t grow = (size_t)(mb * BM + p * 64 + row);
            const size_t gcol = (size_t)(nb * BN + (lane & 31) * 4);
            *(f32x4*)&O[grow * N_DIM + gcol] = v;
        }
    }
}

// ---------------- fallback: reg staging + in-loop convert ----------------

#define FBM 128
#define FBN 128
#define FBK 32
#define FNSTEPS (K_DIM / FBK)
#define FMB (M_DIM / FBM)
#define FNB (N_DIM / FBN)
#define FNWG (FMB * FNB)

__global__ __launch_bounds__(256, 2)
void lmhead_gemm_conv(const float* __restrict__ X,
                      const int* __restrict__ Wq,
                      const float* __restrict__ S,
                      float* __restrict__ O)
{
    __shared__ unsigned short Alds[2][FBM][FBK];
    __shared__ unsigned short Blds[2][FBN][FBK];

    const int tid  = threadIdx.x;
    const int lane = tid & 63;
    const int wave = tid >> 6;
    const int wr   = wave >> 1;
    const int wc   = wave & 1;

    const int bid = blockIdx.x;
    const int wg  = (bid & 7) * (FNWG / 8) + (bid >> 3);
    const int mb  = wg % FMB;
    const int nb  = wg / FMB;

    const int srow = tid >> 1;
    const int skh  = (tid & 1) * 16;

    const float* aptr = X  + (size_t)(mb * FBM + srow) * K_DIM + skh;
    const int*   wptr = Wq + (size_t)(nb * FBN + srow) * K_DIM + skh;

    f32x4 av[4];
    i32x4 wv[4];

    auto load_tiles = [&](int k0) {
        const f32x4* ap = (const f32x4*)(aptr + k0);
        const i32x4* wp = (const i32x4*)(wptr + k0);
        av[0] = ap[0]; av[1] = ap[1]; av[2] = ap[2]; av[3] = ap[3];
        wv[0] = wp[0]; wv[1] = wp[1]; wv[2] = wp[2]; wv[3] = wp[3];
    };

    auto stage = [&](int buf) {
        unsigned int apk[8], wpk[8];
        #pragma unroll
        for (int i = 0; i < 8; ++i) {
            apk[i] = pack2(av[(2*i) >> 2][(2*i) & 3], av[(2*i+1) >> 2][(2*i+1) & 3]);
            wpk[i] = pack2((float)wv[(2*i) >> 2][(2*i) & 3], (float)wv[(2*i+1) >> 2][(2*i+1) & 3]);
        }
        *(u32x4*)&Alds[buf][srow][skh]     = u32x4{apk[0], apk[1], apk[2], apk[3]};
        *(u32x4*)&Alds[buf][srow][skh + 8] = u32x4{apk[4], apk[5], apk[6], apk[7]};
        *(u32x4*)&Blds[buf][srow][skh]     = u32x4{wpk[0], wpk[1], wpk[2], wpk[3]};
        *(u32x4*)&Blds[buf][srow][skh + 8] = u32x4{wpk[4], wpk[5], wpk[6], wpk[7]};
    };

    f32x4 acc[4][4];
    #pragma unroll
    for (int i = 0; i < 4; ++i)
        #pragma unroll
        for (int j = 0; j < 4; ++j)
            acc[i][j] = f32x4{0.f, 0.f, 0.f, 0.f};

    load_tiles(0);
    stage(0);
    __syncthreads();

    int cur = 0;
    for (int s = 0; s < FNSTEPS; ++s) {
        if (s + 1 < FNSTEPS) load_tiles((s + 1) * FBK);

        bf16x8 af[4], bfr[4];
        const int arow = wr * 64 + (lane & 15);
        const int brow = wc * 64 + (lane & 15);
        const int kb   = (lane >> 4) * 8;
        #pragma unroll
        for (int mf = 0; mf < 4; ++mf)
            af[mf] = *(const bf16x8*)&Alds[cur][arow + mf * 16][kb];
        #pragma unroll
        for (int nf = 0; nf < 4; ++nf)
            bfr[nf] = *(const bf16x8*)&Blds[cur][brow + nf * 16][kb];

        #pragma unroll
        for (int mf = 0; mf < 4; ++mf)
            #pragma unroll
            for (int nf = 0; nf < 4; ++nf)
                acc[mf][nf] = __builtin_amdgcn_mfma_f32_16x16x32_bf16(
                    af[mf], bfr[nf], acc[mf][nf], 0, 0, 0);

        if (s + 1 < FNSTEPS) stage(cur ^ 1);
        __syncthreads();
        cur ^= 1;
    }

    #pragma unroll
    for (int nf = 0; nf < 4; ++nf) {
        const int n = nb * FBN + wc * 64 + nf * 16 + (lane & 15);
        const float sc = S[n];
        #pragma unroll
        for (int mf = 0; mf < 4; ++mf) {
            const int m0 = mb * FBM + wr * 64 + mf * 16 + ((lane >> 4) << 2);
            #pragma unroll
            for (int r = 0; r < 4; ++r)
                O[(size_t)(m0 + r) * N_DIM + n] = acc[mf][nf][r] * sc;
        }
    }
}

// ---------------- launch ----------------

extern "C" void kernel_launch(void* const* d_in, const int* in_sizes, int n_in,
                              void* d_out, int out_size, void* d_ws, size_t ws_size,
                              hipStream_t stream) {
    const float* X  = (const float*)d_in[0];
    const int*   Wq = (const int*)d_in[1];
    const float* S  = (const float*)d_in[2];
    float*       O  = (float*)d_out;

    const size_t XB_BYTES = (size_t)M_DIM * K_DIM * 2;
    const size_t WB_BYTES = (size_t)N_DIM * K_DIM * 2;

    if (ws_size >= XB_BYTES + WB_BYTES) {
        unsigned short* Xb = (unsigned short*)d_ws;
        unsigned short* Wb = (unsigned short*)((char*)d_ws + XB_BYTES);
        cvt_x_kernel<<<896, 256, 0, stream>>>(X, Xb);
        cvt_w_kernel<<<2048, 256, 0, stream>>>(Wq, Wb);
        lmhead_gemm_3b<<<NWG, 256, 0, stream>>>(Xb, Wb, S, O);
    } else {
        lmhead_gemm_conv<<<FNWG, 256, 0, stream>>>(X, Wq, S, O);
    }
}